// Round 8
// baseline (516.615 us; speedup 1.0000x reference)
//
#include <hip/hip_runtime.h>
#include <math.h>

#define DIM 128
#define TPB 256
#define PREP_GRID 2048
#define NXCD 8
#define SUB_XC 3                  // slots per (row, xcd-seg), sub edges (avg 1)
#define SUP_XC 8                  // slots per (row, xcd-seg), sup edges (avg 4) = one 64B line
#define SUB_CAP (NXCD * SUB_XC)   // 24 per row
#define SUP_CAP (NXCD * SUP_XC)   // 64 per row
#define OVER_MAX 32768

// ---------------- prep: sim partials + diff + XCD-segmented bucket binning ----------------
__global__ void prep_bin_kernel(const float* __restrict__ inputs,
                                const float* __restrict__ old_act,
                                const int* __restrict__ fields,
                                const int* __restrict__ sub_rows, const int* __restrict__ sub_cols,
                                const float* __restrict__ sub_vals, int e_sub,
                                const int* __restrict__ sup_rows, const int* __restrict__ sup_cols,
                                const float* __restrict__ sup_vals, int e_sup,
                                int* __restrict__ cnt_sub,   // [NXCD][nrows]
                                int* __restrict__ cnt_sup,   // [NXCD][nrows]
                                int* __restrict__ over_cnt,  // [1]
                                int2* __restrict__ pk_sub,   // [nrows][SUB_CAP]
                                int2* __restrict__ pk_sup,   // [nrows][SUP_CAP]
                                int4* __restrict__ over,
                                float* __restrict__ partials,
                                float* __restrict__ diff,
                                int nrows, int n2) {
    int tid = blockIdx.x * blockDim.x + threadIdx.x;
    int stride = gridDim.x * blockDim.x;
    int seg = blockIdx.x & (NXCD - 1);   // XCD-locality heuristic (perf only)

    // sim + diff precompute
    float dot = 0.f, nx = 0.f, ny = 0.f;
    for (int i = tid; i < n2; i += stride) {
        int idx = i * 2;
        int b = idx >> 7, d = idx & (DIM - 1);
        float2 x = *(const float2*)(inputs + idx);
        int f = fields[b];
        float2 y = *(const float2*)(old_act + (size_t)f * DIM + d);
        dot += x.x * y.x + x.y * y.y;
        nx  += x.x * x.x + x.y * x.y;
        ny  += y.x * y.x + y.y * y.y;
        *(float2*)(diff + idx) = make_float2(x.x - y.x, x.y - y.y);
    }

    // bin edges into per-(row, seg) slot ranges
    int e_tot = e_sub + e_sup;
    for (int i = tid; i < e_tot; i += stride) {
        if (i < e_sub) {
            int r = sub_rows[i], c = sub_cols[i];
            float v = sub_vals[i];
            int pos = atomicAdd(&cnt_sub[(size_t)seg * nrows + r], 1);
            if (pos < SUB_XC)
                pk_sub[(size_t)r * SUB_CAP + seg * SUB_XC + pos] = make_int2(c, __float_as_int(v));
            else {
                int op = atomicAdd(over_cnt, 1);
                if (op < OVER_MAX) over[op] = make_int4(r, c, __float_as_int(v), 0);
            }
        } else {
            int k = i - e_sub;
            int r = sup_rows[k], c = sup_cols[k];
            float v = sup_vals[k];
            int pos = atomicAdd(&cnt_sup[(size_t)seg * nrows + r], 1);
            if (pos < SUP_XC)
                pk_sup[(size_t)r * SUP_CAP + seg * SUP_XC + pos] = make_int2(c, __float_as_int(v));
            else {
                int op = atomicAdd(over_cnt, 1);
                if (op < OVER_MAX) over[op] = make_int4(r, c, __float_as_int(v), 1);
            }
        }
    }

    // block-reduce sim
    for (int off = 32; off > 0; off >>= 1) {
        dot += __shfl_down(dot, off, 64);
        nx  += __shfl_down(nx,  off, 64);
        ny  += __shfl_down(ny,  off, 64);
    }
    __shared__ float s[3][4];
    int lane = threadIdx.x & 63, wv = threadIdx.x >> 6;
    if (lane == 0) { s[0][wv] = dot; s[1][wv] = nx; s[2][wv] = ny; }
    __syncthreads();
    if (threadIdx.x == 0) {
        float D = 0.f, NX = 0.f, NY = 0.f;
        for (int w = 0; w < 4; ++w) { D += s[0][w]; NX += s[1][w]; NY += s[2][w]; }
        partials[blockIdx.x * 3 + 0] = D;
        partials[blockIdx.x * 3 + 1] = NX;
        partials[blockIdx.x * 3 + 2] = NY;
    }
}

// ---------------- row accumulate: wave per row, walk 8 segments per list ----------------
__global__ void row_bucket_kernel(const int* __restrict__ cnt_sub, const int* __restrict__ cnt_sup,
                                  const int2* __restrict__ pk_sub, const int2* __restrict__ pk_sup,
                                  const float* __restrict__ diff, const float* __restrict__ old_act,
                                  float* __restrict__ out, int nrows) {
    int wv = threadIdx.x >> 6, lane = threadIdx.x & 63;
    int r = blockIdx.x * (blockDim.x >> 6) + wv;
    if (r >= nrows) return;
    const int d0 = lane * 2;
    float a0 = 0.f, a1 = 0.f;

    // sub edges: v * diff[c]
    {
        const int2* bs = pk_sub + (size_t)r * SUB_CAP;
        for (int x = 0; x < NXCD; ++x) {
            int e = cnt_sub[(size_t)x * nrows + r]; if (e > SUB_XC) e = SUB_XC;
            const int2* bp = bs + x * SUB_XC;
            for (int j = 0; j < e; ++j) {
                int2 p = bp[j];
                float2 y = *(const float2*)(diff + (size_t)p.x * DIM + d0);
                float v = __int_as_float(p.y);
                a0 += v * y.x;
                a1 += v * y.y;
            }
        }
    }
    // sup edges: v * old_act[c], 4-wide unrolled within segment
    {
        const int2* bs = pk_sup + (size_t)r * SUP_CAP;
        for (int x = 0; x < NXCD; ++x) {
            int e = cnt_sup[(size_t)x * nrows + r]; if (e > SUP_XC) e = SUP_XC;
            const int2* bp = bs + x * SUP_XC;
            int j = 0;
            for (; j + 4 <= e; j += 4) {
                int2 p0 = bp[j], p1 = bp[j + 1], p2 = bp[j + 2], p3 = bp[j + 3];
                float2 y0 = *(const float2*)(old_act + (size_t)p0.x * DIM + d0);
                float2 y1 = *(const float2*)(old_act + (size_t)p1.x * DIM + d0);
                float2 y2 = *(const float2*)(old_act + (size_t)p2.x * DIM + d0);
                float2 y3 = *(const float2*)(old_act + (size_t)p3.x * DIM + d0);
                a0 += __int_as_float(p0.y) * y0.x; a1 += __int_as_float(p0.y) * y0.y;
                a0 += __int_as_float(p1.y) * y1.x; a1 += __int_as_float(p1.y) * y1.y;
                a0 += __int_as_float(p2.y) * y2.x; a1 += __int_as_float(p2.y) * y2.y;
                a0 += __int_as_float(p3.y) * y3.x; a1 += __int_as_float(p3.y) * y3.y;
            }
            for (; j < e; ++j) {
                int2 p = bp[j];
                float2 y = *(const float2*)(old_act + (size_t)p.x * DIM + d0);
                a0 += __int_as_float(p.y) * y.x;
                a1 += __int_as_float(p.y) * y.y;
            }
        }
    }
    *(float2*)(out + (size_t)r * DIM + d0) = make_float2(a0, a1);
}

// ---------------- tail: sim finalize + overflow edges (wave per edge) ----------------
__global__ void tail_kernel(const float* __restrict__ partials, int np,
                            const int* __restrict__ over_cnt, const int4* __restrict__ over,
                            const float* __restrict__ diff, const float* __restrict__ old_act,
                            float* __restrict__ out, int n) {
    if (blockIdx.x == 0 && threadIdx.x < 64) {
        double dot = 0.0, nxs = 0.0, nys = 0.0;
        for (int i = threadIdx.x; i < np; i += 64) {
            dot += (double)partials[i * 3 + 0];
            nxs += (double)partials[i * 3 + 1];
            nys += (double)partials[i * 3 + 2];
        }
        for (int off = 32; off > 0; off >>= 1) {
            dot += __shfl_down(dot, off, 64);
            nxs += __shfl_down(nxs, off, 64);
            nys += __shfl_down(nys, off, 64);
        }
        if (threadIdx.x == 0)
            out[n] = (float)(dot / (sqrt(nxs) * sqrt(nys)));
    }
    int no = *over_cnt; if (no > OVER_MAX) no = OVER_MAX;
    int lane = threadIdx.x & 63;
    int gw = (blockIdx.x * blockDim.x + threadIdx.x) >> 6;
    int nw = (gridDim.x * blockDim.x) >> 6;
    int d0 = lane * 2;
    for (int e = gw; e < no; e += nw) {
        int4 t = over[e];
        float v = __int_as_float(t.z);
        const float* src = t.w ? old_act : diff;
        float2 y = *(const float2*)(src + (size_t)t.y * DIM + d0);
        float* o = out + (size_t)t.x * DIM + d0;
        atomicAdd(o,     v * y.x);
        atomicAdd(o + 1, v * y.y);
    }
}

// ---------------- fallback (atomic path, any ws size) ----------------
__global__ void zero_out_kernel(float* __restrict__ out, int n) {
    int i = blockIdx.x * blockDim.x + threadIdx.x;
    if (i < n) out[i] = 0.f;
}
__global__ void sim_atomic_kernel(const float* __restrict__ inputs,
                                  const float* __restrict__ old_act,
                                  const int* __restrict__ fields,
                                  float* __restrict__ out_sim, int n2) {
    __shared__ double sd[3];
    if (threadIdx.x == 0) { sd[0] = 0; sd[1] = 0; sd[2] = 0; }
    __syncthreads();
    float dot = 0.f, nx = 0.f, ny = 0.f;
    for (int i = threadIdx.x; i < n2; i += blockDim.x) {
        int idx = i * 2;
        int b = idx >> 7, d = idx & (DIM - 1);
        float2 x = *(const float2*)(inputs + idx);
        int f = fields[b];
        float2 y = *(const float2*)(old_act + (size_t)f * DIM + d);
        dot += x.x * y.x + x.y * y.y;
        nx  += x.x * x.x + x.y * x.y;
        ny  += y.x * y.x + y.y * y.y;
    }
    for (int off = 32; off > 0; off >>= 1) {
        dot += __shfl_down(dot, off, 64);
        nx  += __shfl_down(nx,  off, 64);
        ny  += __shfl_down(ny,  off, 64);
    }
    if ((threadIdx.x & 63) == 0) {
        atomicAdd(&sd[0], (double)dot);
        atomicAdd(&sd[1], (double)nx);
        atomicAdd(&sd[2], (double)ny);
    }
    __syncthreads();
    if (threadIdx.x == 0)
        *out_sim = (float)(sd[0] / (sqrt(sd[1]) * sqrt(sd[2])));
}
__global__ void spmm_sub_atomic(const int* __restrict__ rows, const int* __restrict__ cols,
                                const float* __restrict__ vals, const float* __restrict__ inputs,
                                const float* __restrict__ old_act, const int* __restrict__ fields,
                                float* __restrict__ out, int ne) {
    int t = blockIdx.x * blockDim.x + threadIdx.x;
    int e = t >> 6, lane = t & 63;
    if (e >= ne) return;
    int r = rows[e], c = cols[e];
    float v = vals[e];
    int f = fields[c];
    int d0 = lane * 2;
    const float2 x = *(const float2*)(inputs  + (size_t)c * DIM + d0);
    const float2 y = *(const float2*)(old_act + (size_t)f * DIM + d0);
    float* o = out + (size_t)r * DIM + d0;
    atomicAdd(o,     v * (x.x - y.x));
    atomicAdd(o + 1, v * (x.y - y.y));
}
__global__ void spmm_sup_atomic(const int* __restrict__ rows, const int* __restrict__ cols,
                                const float* __restrict__ vals, const float* __restrict__ old_act,
                                float* __restrict__ out, int ne) {
    int t = blockIdx.x * blockDim.x + threadIdx.x;
    int e = t >> 6, lane = t & 63;
    if (e >= ne) return;
    int r = rows[e], c = cols[e];
    float v = vals[e];
    int d0 = lane * 2;
    const float2 y = *(const float2*)(old_act + (size_t)c * DIM + d0);
    float* o = out + (size_t)r * DIM + d0;
    atomicAdd(o,     v * y.x);
    atomicAdd(o + 1, v * y.y);
}

extern "C" void kernel_launch(void* const* d_in, const int* in_sizes, int n_in,
                              void* d_out, int out_size, void* d_ws, size_t ws_size,
                              hipStream_t stream) {
    const float* inputs   = (const float*)d_in[0];
    const float* old_act  = (const float*)d_in[1];
    const int*   fields   = (const int*)d_in[2];
    const int*   sub_rows = (const int*)d_in[3];
    const int*   sub_cols = (const int*)d_in[4];
    const float* sub_vals = (const float*)d_in[5];
    const int*   sup_rows = (const int*)d_in[6];
    const int*   sup_cols = (const int*)d_in[7];
    const float* sup_vals = (const float*)d_in[8];

    const int n     = in_sizes[0];     // BATCH * DIM
    const int nrows = n / DIM;         // BATCH
    const int e_sub = in_sizes[3];
    const int e_sup = in_sizes[6];

    float* out = (float*)d_out;
    char*  ws  = (char*)d_ws;

    // ---- workspace layout ----
    size_t off_part = 0;                                        // f32[PREP_GRID*3]
    size_t off_cnt  = (PREP_GRID * 3 * 4 + 63) & ~(size_t)63;   // int[16*nrows + 1]
    size_t off_over = (off_cnt + ((size_t)16 * nrows + 1) * 4 + 15) & ~(size_t)15;  // int4[OVER_MAX]
    size_t off_psub = off_over + (size_t)OVER_MAX * 16;         // int2[nrows*SUB_CAP]
    size_t off_psup = off_psub + (size_t)nrows * SUB_CAP * 8;   // int2[nrows*SUP_CAP]
    size_t off_diff = off_psup + (size_t)nrows * SUP_CAP * 8;   // f32[n]
    size_t need     = off_diff + (size_t)n * 4;

    if (ws_size >= need) {
        float* partials = (float*)(ws + off_part);
        int*   cnt_sub  = (int*)(ws + off_cnt);
        int*   cnt_sup  = cnt_sub + (size_t)NXCD * nrows;
        int*   over_cnt = cnt_sub + (size_t)16 * nrows;
        int4*  over     = (int4*)(ws + off_over);
        int2*  pk_sub   = (int2*)(ws + off_psub);
        int2*  pk_sup   = (int2*)(ws + off_psup);
        float* diff     = (float*)(ws + off_diff);

        hipMemsetAsync(cnt_sub, 0, ((size_t)16 * nrows + 1) * 4, stream);

        prep_bin_kernel<<<PREP_GRID, TPB, 0, stream>>>(
            inputs, old_act, fields,
            sub_rows, sub_cols, sub_vals, e_sub,
            sup_rows, sup_cols, sup_vals, e_sup,
            cnt_sub, cnt_sup, over_cnt, pk_sub, pk_sup, over,
            partials, diff, nrows, n / 2);

        row_bucket_kernel<<<(nrows + 3) / 4, TPB, 0, stream>>>(
            cnt_sub, cnt_sup, pk_sub, pk_sup, diff, old_act, out, nrows);

        tail_kernel<<<64, TPB, 0, stream>>>(
            partials, PREP_GRID, over_cnt, over, diff, old_act, out, n);
    } else {
        // fallback: atomic path, needs no workspace
        zero_out_kernel<<<(n + 255) / 256, 256, 0, stream>>>(out, n);
        {
            long long threads = (long long)e_sub * 64;
            spmm_sub_atomic<<<(int)((threads + 255) / 256), 256, 0, stream>>>(
                sub_rows, sub_cols, sub_vals, inputs, old_act, fields, out, e_sub);
        }
        {
            long long threads = (long long)e_sup * 64;
            spmm_sup_atomic<<<(int)((threads + 255) / 256), 256, 0, stream>>>(
                sup_rows, sup_cols, sup_vals, old_act, out, e_sup);
        }
        sim_atomic_kernel<<<1, 1024, 0, stream>>>(inputs, old_act, fields, out + n, n / 2);
    }
}